// Round 23
// baseline (92.095 us; speedup 1.0000x reference)
//
#include <hip/hip_runtime.h>

#define T_    16
#define M_    256
#define HW_   1024
#define DM    512
#define H_    8
#define HEAD_ 64
#define LOG2E 1.4426950408889634f

typedef __attribute__((ext_vector_type(8))) short short8;
typedef __attribute__((ext_vector_type(4))) float f32x4;

__device__ __forceinline__ unsigned cvtpk(float lo, float hi) {
    unsigned r;
    asm("v_cvt_pk_bf16_f32 %0, %1, %2" : "=v"(r) : "v"(lo), "v"(hi));
    return r;
}

// bare v_exp_f32 (2^x); s_nop 1 covers the TRANS->VALU read hazard.
__device__ __forceinline__ float fexp2(float x) {
    float r;
    asm("v_exp_f32 %0, %1\n\ts_nop 1" : "=v"(r) : "v"(x));
    return r;
}

__device__ __forceinline__ float b2f(unsigned short u) {
    return __uint_as_float(((unsigned)u) << 16);
}

__device__ __forceinline__ void gload16(const void* g, void* l) {
    __builtin_amdgcn_global_load_lds(
        (const __attribute__((address_space(1))) void*)g,
        (__attribute__((address_space(3))) void*)l, 16, 0, 0);
}

// ---------------------------------------------------------------------------
// Convert all f32 operands to bf16 in one memory-bound pass.
// ---------------------------------------------------------------------------
__global__ __launch_bounds__(256) void cvtall(const float* __restrict__ fpe,
                                              const float* __restrict__ tpe,
                                              const float* __restrict__ utt,
                                              const float* __restrict__ Wq,
                                              const float* __restrict__ Wk,
                                              const float* __restrict__ Wv,
                                              const float* __restrict__ Wo,
                                              unsigned short* __restrict__ Fb,
                                              unsigned short* __restrict__ Tb,
                                              unsigned short* __restrict__ Ub0,
                                              unsigned short* __restrict__ Wbf) {
    size_t e = (size_t)(blockIdx.x * 256 + threadIdx.x) * 8;
    const float* s;
    unsigned short* d;
    if (e < 8388608)        { s = fpe + e;              d = Fb  + e; }
    else if (e < 10485760)  { s = tpe + (e - 8388608);  d = Tb  + (e - 8388608); }
    else if (e < 12582912)  { s = utt + (e - 10485760); d = Ub0 + (e - 10485760); }
    else if (e < 12845056)  { s = Wq  + (e - 12582912); d = Wbf + (e - 12582912 + 0); }
    else if (e < 13107200)  { s = Wk  + (e - 12845056); d = Wbf + (e - 12845056 + 262144); }
    else if (e < 13369344)  { s = Wv  + (e - 13107200); d = Wbf + (e - 13107200 + 524288); }
    else                    { s = Wo  + (e - 13369344); d = Wbf + (e - 13369344 + 786432); }
    float4 a = *reinterpret_cast<const float4*>(s);
    float4 b = *reinterpret_cast<const float4*>(s + 4);
    uint4 v = make_uint4(cvtpk(a.x, a.y), cvtpk(a.z, a.w),
                         cvtpk(b.x, b.y), cvtpk(b.z, b.w));
    *reinterpret_cast<uint4*>(d) = v;
}

// ---------------------------------------------------------------------------
// Merged Q/K/V projections, 64x128 tiles (6 blocks/CU), XCD-grouped.
// ---------------------------------------------------------------------------
__global__ __launch_bounds__(256) void proj3(const unsigned short* __restrict__ Fb,
                                             const unsigned short* __restrict__ Tb,
                                             const unsigned short* __restrict__ Ub0,
                                             const unsigned short* __restrict__ Wbf,
                                             unsigned short* __restrict__ Qb,
                                             unsigned short* __restrict__ Kb,
                                             unsigned short* __restrict__ Vb) {
    __shared__ __align__(16) unsigned char smem[24576];
    unsigned char* As = smem;            // [64 r][64 k] bf16 swz
    unsigned char* Bs = smem + 8192;     // [128 c][64 k] bf16 swz

    const int b  = blockIdx.x;
    const int x  = b & 7;
    const int cp = (b >> 3) & 3;
    const int m  = b >> 5;            // 0..47
    const int p  = x * 48 + m;        // 0..383 unique
    const unsigned short *X, *W;
    unsigned short* C;
    int r0;
    if (p < 256)      { X = Fb;  W = Wbf;          C = Qb; r0 = p * 64; }
    else if (p < 320) { X = Tb;  W = Wbf + 262144; C = Kb; r0 = (p - 256) * 64; }
    else              { X = Ub0; W = Wbf + 524288; C = Vb; r0 = (p - 320) * 64; }
    const int c0 = cp * 128;

    const int tid = threadIdx.x;
    const int l  = tid & 63;
    const int wid = tid >> 6;
    const int wr = wid >> 1, wc = wid & 1;
    const int g = l >> 4;
    const int c = l & 15;

    f32x4 acc[2][4] = {};

    for (int k0 = 0; k0 < DM; k0 += 64) {
        #pragma unroll
        for (int i = 0; i < 2; ++i) {
            int idx = tid + i * 256;
            int row = idx >> 3, jj = idx & 7;
            int j = jj ^ (row & 7);
            gload16(X + (size_t)(r0 + row) * DM + k0 + j * 8, As + idx * 16);
        }
        #pragma unroll
        for (int i = 0; i < 4; ++i) {
            int idx = tid + i * 256;
            int row = idx >> 3, jj = idx & 7;
            int j = jj ^ (row & 7);
            gload16(W + (size_t)(c0 + row) * DM + k0 + j * 8, Bs + idx * 16);
        }
        __syncthreads();

        #pragma unroll
        for (int ks = 0; ks < 2; ++ks) {
            short8 af[2], bfr[4];
            #pragma unroll
            for (int mm = 0; mm < 2; ++mm) {
                int rq = wr * 32 + mm * 16 + c;
                af[mm] = *reinterpret_cast<short8*>(
                    As + ((rq * 128 + ks * 64 + g * 16) ^ ((rq & 7) << 4)));
            }
            #pragma unroll
            for (int n = 0; n < 4; ++n) {
                int rn = wc * 64 + n * 16 + c;
                bfr[n] = *reinterpret_cast<short8*>(
                    Bs + ((rn * 128 + ks * 64 + g * 16) ^ ((rn & 7) << 4)));
            }
            #pragma unroll
            for (int mm = 0; mm < 2; ++mm)
                #pragma unroll
                for (int n = 0; n < 4; ++n)
                    acc[mm][n] = __builtin_amdgcn_mfma_f32_16x16x32_bf16(
                        af[mm], bfr[n], acc[mm][n], 0, 0, 0);
        }
        __syncthreads();
    }

    #pragma unroll
    for (int mm = 0; mm < 2; ++mm)
        #pragma unroll
        for (int n = 0; n < 4; ++n)
            #pragma unroll
            for (int r = 0; r < 4; ++r)
                C[(size_t)(r0 + wr * 32 + mm * 16 + g * 4 + r) * DM +
                  c0 + wc * 64 + n * 16 + c] =
                    (unsigned short)cvtpk(acc[mm][n][r], acc[mm][n][r]);
}

// ---------------------------------------------------------------------------
// Out-projection, 64x128 tiles (4 blocks/CU), XCD-grouped.
// ---------------------------------------------------------------------------
__global__ __launch_bounds__(256) void gemm_bb(const unsigned short* __restrict__ X,
                                               const unsigned short* __restrict__ W,
                                               float* __restrict__ C) {
    __shared__ __align__(16) unsigned char smem[24576];
    unsigned char* As = smem;
    unsigned char* Bs = smem + 8192;

    const int b  = blockIdx.x;
    const int x  = b & 7;
    const int cp = (b >> 3) & 3;
    const int m  = b >> 5;            // 0..31
    const int p  = x * 32 + m;        // 0..255 unique
    const int r0 = p * 64;
    const int c0 = cp * 128;

    const int tid = threadIdx.x;
    const int l  = tid & 63;
    const int wid = tid >> 6;
    const int wr = wid >> 1, wc = wid & 1;
    const int g = l >> 4;
    const int c = l & 15;

    f32x4 acc[2][4] = {};

    for (int k0 = 0; k0 < DM; k0 += 64) {
        #pragma unroll
        for (int i = 0; i < 2; ++i) {
            int idx = tid + i * 256;
            int row = idx >> 3, jj = idx & 7;
            int j = jj ^ (row & 7);
            gload16(X + (size_t)(r0 + row) * DM + k0 + j * 8, As + idx * 16);
        }
        #pragma unroll
        for (int i = 0; i < 4; ++i) {
            int idx = tid + i * 256;
            int row = idx >> 3, jj = idx & 7;
            int j = jj ^ (row & 7);
            gload16(W + (size_t)(c0 + row) * DM + k0 + j * 8, Bs + idx * 16);
        }
        __syncthreads();

        #pragma unroll
        for (int ks = 0; ks < 2; ++ks) {
            short8 af[2], bfr[4];
            #pragma unroll
            for (int mm = 0; mm < 2; ++mm) {
                int rq = wr * 32 + mm * 16 + c;
                af[mm] = *reinterpret_cast<short8*>(
                    As + ((rq * 128 + ks * 64 + g * 16) ^ ((rq & 7) << 4)));
            }
            #pragma unroll
            for (int n = 0; n < 4; ++n) {
                int rn = wc * 64 + n * 16 + c;
                bfr[n] = *reinterpret_cast<short8*>(
                    Bs + ((rn * 128 + ks * 64 + g * 16) ^ ((rn & 7) << 4)));
            }
            #pragma unroll
            for (int mm = 0; mm < 2; ++mm)
                #pragma unroll
                for (int n = 0; n < 4; ++n)
                    acc[mm][n] = __builtin_amdgcn_mfma_f32_16x16x32_bf16(
                        af[mm], bfr[n], acc[mm][n], 0, 0, 0);
        }
        __syncthreads();
    }

    #pragma unroll
    for (int mm = 0; mm < 2; ++mm)
        #pragma unroll
        for (int n = 0; n < 4; ++n)
            #pragma unroll
            for (int r = 0; r < 4; ++r)
                C[(size_t)(r0 + wr * 32 + mm * 16 + g * 4 + r) * DM +
                  c0 + wc * 64 + n * 16 + c] = acc[mm][n][r];
}

// ---------------------------------------------------------------------------
// Merged pass: [0,4096) Q row-stats (mu, rs) ; [4096,5120) LN-K with qgamma
// fold (K'' = qgamma*LNk(K)) + per-head kgsum ; [5120,5632) vtrans.
// ---------------------------------------------------------------------------
__global__ __launch_bounds__(256) void normpack(const unsigned short* __restrict__ Qb,
                                                const unsigned short* __restrict__ Kb,
                                                const unsigned short* __restrict__ Vb,
                                                const float* __restrict__ qg,
                                                const float* __restrict__ kg,
                                                float* __restrict__ Qst,
                                                unsigned short* __restrict__ Kbf,
                                                float* __restrict__ kgs,
                                                unsigned short* __restrict__ Vt) {
    __shared__ unsigned short vtile[64][68];
    const int bid = blockIdx.x;
    const int tid = threadIdx.x;

    if (bid < 4096) {
        // ---- Q row stats: mu, rs (LN applied algebraically inside attn) ----
        const int wave = tid / 64;
        const int lane = tid % 64;
        const int row  = bid * 4 + wave;

        short8 xv = *reinterpret_cast<const short8*>(&Qb[(size_t)row * DM + lane * 8]);
        float x[8];
        #pragma unroll
        for (int i = 0; i < 8; ++i) x[i] = b2f((unsigned short)xv[i]);

        float s = 0.f;
        #pragma unroll
        for (int i = 0; i < 8; ++i) s += x[i];
        #pragma unroll
        for (int m = 1; m < 64; m <<= 1) s += __shfl_xor(s, m, 64);
        const float mu = s * (1.0f / 512.0f);

        float vs = 0.f;
        #pragma unroll
        for (int i = 0; i < 8; ++i) { float d = x[i] - mu; vs += d * d; }
        #pragma unroll
        for (int m = 1; m < 64; m <<= 1) vs += __shfl_xor(vs, m, 64);
        const float rs = rsqrtf(vs * (1.0f / 512.0f) + 1e-6f);

        if (lane == 0)
            *reinterpret_cast<float2*>(&Qst[(size_t)row * 2]) = make_float2(mu, rs);
    } else if (bid < 5120) {
        // ---- LN-K (kgamma) then * qgamma ; per-head sums kgs[row][h] ----
        const int wave = tid / 64;
        const int lane = tid % 64;
        const int row  = (bid - 4096) * 4 + wave;

        short8 xv = *reinterpret_cast<const short8*>(&Kb[(size_t)row * DM + lane * 8]);
        float x[8];
        #pragma unroll
        for (int i = 0; i < 8; ++i) x[i] = b2f((unsigned short)xv[i]);

        float s = 0.f;
        #pragma unroll
        for (int i = 0; i < 8; ++i) s += x[i];
        #pragma unroll
        for (int m = 1; m < 64; m <<= 1) s += __shfl_xor(s, m, 64);
        const float mu = s * (1.0f / 512.0f);

        float vs = 0.f;
        #pragma unroll
        for (int i = 0; i < 8; ++i) { float d = x[i] - mu; vs += d * d; }
        #pragma unroll
        for (int m = 1; m < 64; m <<= 1) vs += __shfl_xor(vs, m, 64);
        const float rs = rsqrtf(vs * (1.0f / 512.0f) + 1e-6f);

        float4 g0 = *reinterpret_cast<const float4*>(&kg[lane * 8]);
        float4 g1 = *reinterpret_cast<const float4*>(&kg[lane * 8 + 4]);
        float gv[8] = {g0.x, g0.y, g0.z, g0.w, g1.x, g1.y, g1.z, g1.w};
        float4 q0v = *reinterpret_cast<const float4*>(&qg[lane * 8]);
        float4 q1v = *reinterpret_cast<const float4*>(&qg[lane * 8 + 4]);
        float qv[8] = {q0v.x, q0v.y, q0v.z, q0v.w, q1v.x, q1v.y, q1v.z, q1v.w};

        float y[8];
        float part = 0.f;
        #pragma unroll
        for (int i = 0; i < 8; ++i) {
            y[i] = (x[i] - mu) * rs * gv[i] * qv[i];
            part += y[i];
        }
        uint4 o = make_uint4(cvtpk(y[0], y[1]), cvtpk(y[2], y[3]),
                             cvtpk(y[4], y[5]), cvtpk(y[6], y[7]));
        *reinterpret_cast<uint4*>(&Kbf[(size_t)row * DM + lane * 8]) = o;

        // per-head (8-lane group) sum
        part += __shfl_xor(part, 1, 64);
        part += __shfl_xor(part, 2, 64);
        part += __shfl_xor(part, 4, 64);
        if ((lane & 7) == 0)
            kgs[(size_t)row * 8 + (lane >> 3)] = part;
    } else {
        const int b2 = bid - 5120;
        const int dt = b2 & 7, kt = (b2 >> 3) & 3, t = b2 >> 5;

        #pragma unroll
        for (int i = 0; i < 4; ++i) {
            int idx = tid + i * 256;
            int r = idx >> 4, c4 = idx & 15;
            uint2 v = *reinterpret_cast<const uint2*>(
                &Vb[(size_t)(t * M_ + kt * 64 + r) * DM + dt * 64 + c4 * 4]);
            *reinterpret_cast<uint2*>(&vtile[r][c4 * 4]) = v;
        }
        __syncthreads();
        #pragma unroll
        for (int i = 0; i < 4; ++i) {
            int idx = tid + i * 256;
            int r = idx >> 4, c4 = idx & 15;
            unsigned a0 = vtile[c4 * 4 + 0][r], a1 = vtile[c4 * 4 + 1][r];
            unsigned a2 = vtile[c4 * 4 + 2][r], a3 = vtile[c4 * 4 + 3][r];
            uint2 o = make_uint2(a0 | (a1 << 16), a2 | (a3 << 16));
            *reinterpret_cast<uint2*>(
                &Vt[((size_t)t * DM + dt * 64 + r) * M_ + kt * 64 + c4 * 4]) = o;
        }
    }
}

// ---------------------------------------------------------------------------
// MFMA attention: raw-Q QK^T with LN folded algebraically:
// exponent = aq*qk_raw + bq*kgs_k + bias_k,  aq = 0.125*L*rs_q, bq = -mu_q*aq.
// ---------------------------------------------------------------------------
__global__ __launch_bounds__(512, 4) void attn_mfma(const unsigned short* __restrict__ Qb,
                                                    const float* __restrict__ Qst,
                                                    const unsigned short* __restrict__ Kbf,
                                                    const float* __restrict__ kgs,
                                                    const unsigned short* __restrict__ VtG,
                                                    const float* __restrict__ tracks,
                                                    const float* __restrict__ fpos,
                                                    unsigned short* __restrict__ Ubf) {
    const int b   = blockIdx.x;            // 0..1023
    const int xcd = b & 7;
    const int bi  = b >> 3;                // 0..127
    const int qt  = bi & 7;                // 128-q tile 0..7
    const int pp  = xcd + (bi >> 3) * 8;   // 0..127 = t*8 + h
    const int t   = pp >> 3;
    const int h   = pp & 7;
    const int q0  = qt * 128;
    const int tid = threadIdx.x;

    __shared__ __align__(16) unsigned char smem[32768 + 4096 + 1024];
    unsigned char* KV = smem;                        // K [256k][64d] / V [64dv][256k]
    float* tx4 = (float*)(smem + 32768);
    float* ty4 = (float*)(smem + 32768 + 1024);
    float* tz2 = (float*)(smem + 32768 + 2048);
    float* kg4 = (float*)(smem + 32768 + 3072);      // 256: kgs[k][h]
    float* fps = (float*)(smem + 32768 + 4096);      // 128 q x {x,y}

    const int l  = tid & 63;
    const int wq = tid >> 6;    // 0..7
    const int g  = l >> 4;
    const int c  = l & 15;

    // ---- raw Q B-fragments + per-row LN stats ----
    const unsigned short* qrow =
        Qb + (size_t)(t * HW_ + q0 + wq * 16 + c) * DM + h * HEAD_;
    short8 bQ0 = *reinterpret_cast<const short8*>(qrow + g * 8);
    short8 bQ1 = *reinterpret_cast<const short8*>(qrow + 32 + g * 8);
    float2 st = *reinterpret_cast<const float2*>(
        &Qst[(size_t)(t * HW_ + q0 + wq * 16 + c) * 2]);
    const float aq = 0.125f * LOG2E * st.y;
    const float bq = -st.x * aq;

    // ---- stage K via global_load_lds (512 threads -> 4 iters) ----
    #pragma unroll
    for (int it = 0; it < 4; ++it) {
        int idx = tid + it * 512;               // 0..2047
        int row = idx >> 3, jj = idx & 7;
        int j = jj ^ (row & 7);
        gload16(Kbf + (size_t)(t * M_ + row) * DM + h * HEAD_ + j * 8, KV + idx * 16);
    }
    if (tid < 256) {
        float2 tk = *reinterpret_cast<const float2*>(&tracks[t * 512 + tid * 2]);
        tx4[tid] = tk.x * (4.0f * LOG2E);
        ty4[tid] = tk.y * (4.0f * LOG2E);
        tz2[tid] = -2.0f * LOG2E * (tk.x * tk.x + tk.y * tk.y);
        kg4[tid] = kgs[(size_t)(t * M_ + tid) * 8 + h];
        fps[tid] = fpos[q0 * 2 + tid];          // 256 floats = 128 q positions
    }
    __syncthreads();

    // ---- scores^T: acc[n][r] = S_raw[key=n*16+g*4+r][q=q0+wq*16+c] ----
    f32x4 acc[16];
    __builtin_amdgcn_s_setprio(1);
    #pragma unroll
    for (int n = 0; n < 16; ++n) {
        int rk = n * 16 + c;
        short8 a0 = *reinterpret_cast<short8*>(KV + ((rk * 128 + g * 16) ^ ((rk & 7) << 4)));
        short8 a1 = *reinterpret_cast<short8*>(KV + ((rk * 128 + 64 + g * 16) ^ ((rk & 7) << 4)));
        f32x4 z = {0.f, 0.f, 0.f, 0.f};
        z = __builtin_amdgcn_mfma_f32_16x16x32_bf16(a0, bQ0, z, 0, 0, 0);
        z = __builtin_amdgcn_mfma_f32_16x16x32_bf16(a1, bQ1, z, 0, 0, 0);
        acc[n] = z;
    }
    __builtin_amdgcn_s_setprio(0);

    __syncthreads();   // all waves done reading K -> safe to overwrite with V

    // ---- issue V staging NOW; latency hides under bias+exp2+pack+sum ----
    #pragma unroll
    for (int it = 0; it < 4; ++it) {
        int idx = tid + it * 512;               // 0..2047
        int row = idx >> 5, kcc = idx & 31;
        int kc = kcc ^ (row & 7);
        gload16(VtG + ((size_t)t * DM + h * HEAD_ + row) * M_ + kc * 8, KV + idx * 16);
    }

    // ---- LN-fold + bias + exp2 + pack + per-n partial sums ----
    const float fx = fps[(wq * 16 + c) * 2];
    const float fy = fps[(wq * 16 + c) * 2 + 1];
    const float fz = -2.0f * LOG2E * (fx * fx + fy * fy);   // true-bias term
    unsigned pk[16][2];
    float vr[16];
    #pragma unroll
    for (int n = 0; n < 16; ++n) {
        float4 x4 = *reinterpret_cast<float4*>(&tx4[n * 16 + g * 4]);
        float4 y4 = *reinterpret_cast<float4*>(&ty4[n * 16 + g * 4]);
        float4 z4 = *reinterpret_cast<float4*>(&tz2[n * 16 + g * 4]);
        float4 k4 = *reinterpret_cast<float4*>(&kg4[n * 16 + g * 4]);
        float e0 = fexp2(fmaf(aq, acc[n][0],
                    fz + fmaf(bq, k4.x, fmaf(fx, x4.x, fmaf(fy, y4.x, z4.x)))));
        float e1 = fexp2(fmaf(aq, acc[n][1],
                    fz + fmaf(bq, k4.y, fmaf(fx, x4.y, fmaf(fy, y4.y, z4.y)))));
        float e2 = fexp2(fmaf(aq, acc[n][2],
                    fz + fmaf(bq, k4.z, fmaf(fx, x4.z, fmaf(fy, y4.z, z4.z)))));
        float e3 = fexp2(fmaf(aq, acc[n][3],
                    fz + fmaf(bq, k4.w, fmaf(fx, x4.w, fmaf(fy, y4.w, z4.w)))));
        pk[n][0] = cvtpk(e0, e1);
        pk[n][1] = cvtpk(e2, e3);
        vr[n] = (e0 + e1) + (e2 + e3);
    }

    // ---- sum tree + cross-g reduce; inv applied at output ----
    #pragma unroll
    for (int s = 8; s >= 1; s >>= 1)
        #pragma unroll
        for (int n = 0; n < 8; ++n)
            if (n < s) vr[n] += vr[n + s];
    float sum = vr[0];
    sum += __shfl_xor(sum, 16, 64);
    sum += __shfl_xor(sum, 32, 64);
    const float inv = 1.0f / sum;    // row q = q0 + wq*16 + c

    // output rows are q = q0 + wq*16 + g*4 + r -> fetch inv from lane c'=g*4+r
    float invr[4];
    #pragma unroll
    for (int r = 0; r < 4; ++r)
        invr[r] = __shfl(inv, (l & 48) | ((l >> 2) & 12) | r, 64);

    __syncthreads();   // V staged (barrier drains vmcnt)

    // ---- PV ----
    f32x4 o[4] = {{0.f,0.f,0.f,0.f},{0.f,0.f,0.f,0.f},{0.f,0.f,0.f,0.f},{0.f,0.f,0.f,0.f}};
    __builtin_amdgcn_s_setprio(1);
    #pragma unroll
    for (int ks = 0; ks < 8; ++ks) {
        unsigned wb[4];
        #pragma unroll
        for (int wt = 0; wt < 4; ++wt) {
            int src = ((l & 16) << 1) + (wt >> 1) * 16 + c;
            unsigned ve = (unsigned)__shfl((int)pk[2 * ks][wt & 1], src, 64);
            unsigned vo = (unsigned)__shfl((int)pk[2 * ks + 1][wt & 1], src, 64);
            wb[wt] = (g < 2) ? ve : vo;
        }
        uint4 uu = make_uint4(wb[0], wb[1], wb[2], wb[3]);
        short8 aP = *reinterpret_cast<short8*>(&uu);
        #pragma unroll
        for (int nv = 0; nv < 4; ++nv) {
            int rv = nv * 16 + c;
            short8 bV = *reinterpret_cast<short8*>(
                KV + ((rv * 512 + ks * 64 + g * 16) ^ ((rv & 7) << 4)));
            o[nv] = __builtin_amdgcn_mfma_f32_16x16x32_bf16(aP, bV, o[nv], 0, 0, 0);
        }
    }
    __builtin_amdgcn_s_setprio(0);

    #pragma unroll
    for (int nv = 0; nv < 4; ++nv)
        #pragma unroll
        for (int r = 0; r < 4; ++r) {
            float xo = o[nv][r] * invr[r];
            Ubf[(size_t)(t * HW_ + q0 + wq * 16 + g * 4 + r) * DM +
                h * HEAD_ + nv * 16 + c] = (unsigned short)cvtpk(xo, xo);
        }
}

// ---------------------------------------------------------------------------
extern "C" void kernel_launch(void* const* d_in, const int* in_sizes, int n_in,
                              void* d_out, int out_size, void* d_ws, size_t ws_size,
                              hipStream_t stream) {
    const float* utt    = (const float*)d_in[0];
    const float* tracks = (const float*)d_in[1];
    const float* fpos   = (const float*)d_in[2];
    const float* fpe    = (const float*)d_in[3];
    const float* tpe    = (const float*)d_in[4];
    const float* Wq     = (const float*)d_in[5];
    const float* Wk     = (const float*)d_in[6];
    const float* Wv     = (const float*)d_in[7];
    const float* Wo     = (const float*)d_in[8];
    const float* qgamma = (const float*)d_in[9];
    const float* kgamma = (const float*)d_in[10];
    float* out = (float*)d_out;

    char* ws = (char*)d_ws;
    unsigned short* Fb  = (unsigned short*)(ws);              // [0, 16.8M) bf16 fpe
    unsigned short* Tb  = (unsigned short*)(ws + 16777216);   // [16.8, 21.0) bf16 tpe
    unsigned short* Ub0 = (unsigned short*)(ws + 20971520);   // [21.0, 25.2) bf16 utt
    unsigned short* Qb  = (unsigned short*)(ws + 25165824);   // [25.2, 42.0) proj Q (raw)
    unsigned short* Kb  = (unsigned short*)(ws + 41943040);   // [42.0, 46.1) proj K
    unsigned short* Vb  = (unsigned short*)(ws + 46137344);   // [46.1, 50.3) proj V
    float*          Qst = (float*)(ws + 50331648);            // [50.3, +131K) mu/rs per Q row
    float*          kgs = (float*)(ws + 50462720);            // [+131K, +262K) kgsum
    unsigned short* Kbf = (unsigned short*)(ws + 67108864);   // [67.1, 71.3) K'' (gamma-folded)
    unsigned short* Vt  = (unsigned short*)(ws + 71303168);   // [71.3, 75.5) V^T
    unsigned short* Wbf = (unsigned short*)(ws + 75497472);   // [75.5, 77.6) weights
    unsigned short* Ubf = (unsigned short*)(ws);              // overlays Fb (dead after proj3)

    // 1) all f32 -> bf16 conversions (memory-bound single pass)
    cvtall<<<6656, 256, 0, stream>>>(fpe, tpe, utt, Wq, Wk, Wv, Wo, Fb, Tb, Ub0, Wbf);

    // 2) Q/K/V projections -> bf16 (64x128 tiles, 6 blocks/CU)
    proj3<<<1536, 256, 0, stream>>>(Fb, Tb, Ub0, Wbf, Qb, Kb, Vb);

    // 3) Q stats, LN-K+qgamma-fold+kgsum, V-transpose
    normpack<<<5632, 256, 0, stream>>>(Qb, Kb, Vb, qgamma, kgamma, Qst, Kbf, kgs, Vt);

    // 4) fused MFMA attention (raw Q, LN folded into exponent)
    attn_mfma<<<1024, 512, 0, stream>>>(Qb, Qst, Kbf, kgs, Vt, tracks, fpos, Ubf);

    // 5) out projection (64x128 tiles, 4 blocks/CU)
    gemm_bb<<<1024, 256, 0, stream>>>(Ubf, Wbf + 786432, out);
}

// Round 24
// 89.148 us; speedup vs baseline: 1.0331x; 1.0331x over previous
//
#include <hip/hip_runtime.h>

#define T_    16
#define M_    256
#define HW_   1024
#define DM    512
#define H_    8
#define HEAD_ 64
#define LOG2E 1.4426950408889634f

typedef __attribute__((ext_vector_type(8))) short short8;
typedef __attribute__((ext_vector_type(4))) float f32x4;

__device__ __forceinline__ unsigned cvtpk(float lo, float hi) {
    unsigned r;
    asm("v_cvt_pk_bf16_f32 %0, %1, %2" : "=v"(r) : "v"(lo), "v"(hi));
    return r;
}

// bare v_exp_f32 (2^x); s_nop 1 covers the TRANS->VALU read hazard.
__device__ __forceinline__ float fexp2(float x) {
    float r;
    asm("v_exp_f32 %0, %1\n\ts_nop 1" : "=v"(r) : "v"(x));
    return r;
}

__device__ __forceinline__ float b2f(unsigned short u) {
    return __uint_as_float(((unsigned)u) << 16);
}

__device__ __forceinline__ void gload16(const void* g, void* l) {
    __builtin_amdgcn_global_load_lds(
        (const __attribute__((address_space(1))) void*)g,
        (__attribute__((address_space(3))) void*)l, 16, 0, 0);
}

// ---------------------------------------------------------------------------
// Convert all f32 operands to bf16 in one memory-bound pass.
// ---------------------------------------------------------------------------
__global__ __launch_bounds__(256) void cvtall(const float* __restrict__ fpe,
                                              const float* __restrict__ tpe,
                                              const float* __restrict__ utt,
                                              const float* __restrict__ Wq,
                                              const float* __restrict__ Wk,
                                              const float* __restrict__ Wv,
                                              const float* __restrict__ Wo,
                                              unsigned short* __restrict__ Fb,
                                              unsigned short* __restrict__ Tb,
                                              unsigned short* __restrict__ Ub0,
                                              unsigned short* __restrict__ Wbf) {
    size_t e = (size_t)(blockIdx.x * 256 + threadIdx.x) * 8;
    const float* s;
    unsigned short* d;
    if (e < 8388608)        { s = fpe + e;              d = Fb  + e; }
    else if (e < 10485760)  { s = tpe + (e - 8388608);  d = Tb  + (e - 8388608); }
    else if (e < 12582912)  { s = utt + (e - 10485760); d = Ub0 + (e - 10485760); }
    else if (e < 12845056)  { s = Wq  + (e - 12582912); d = Wbf + (e - 12582912 + 0); }
    else if (e < 13107200)  { s = Wk  + (e - 12845056); d = Wbf + (e - 12845056 + 262144); }
    else if (e < 13369344)  { s = Wv  + (e - 13107200); d = Wbf + (e - 13107200 + 524288); }
    else                    { s = Wo  + (e - 13369344); d = Wbf + (e - 13369344 + 786432); }
    float4 a = *reinterpret_cast<const float4*>(s);
    float4 b = *reinterpret_cast<const float4*>(s + 4);
    uint4 v = make_uint4(cvtpk(a.x, a.y), cvtpk(a.z, a.w),
                         cvtpk(b.x, b.y), cvtpk(b.z, b.w));
    *reinterpret_cast<uint4*>(d) = v;
}

// ---------------------------------------------------------------------------
// Merged Q/K/V projections, 64x128 tiles (6 blocks/CU), XCD-grouped.
// ---------------------------------------------------------------------------
__global__ __launch_bounds__(256) void proj3(const unsigned short* __restrict__ Fb,
                                             const unsigned short* __restrict__ Tb,
                                             const unsigned short* __restrict__ Ub0,
                                             const unsigned short* __restrict__ Wbf,
                                             unsigned short* __restrict__ Qb,
                                             unsigned short* __restrict__ Kb,
                                             unsigned short* __restrict__ Vb) {
    __shared__ __align__(16) unsigned char smem[24576];
    unsigned char* As = smem;            // [64 r][64 k] bf16 swz
    unsigned char* Bs = smem + 8192;     // [128 c][64 k] bf16 swz

    const int b  = blockIdx.x;
    const int x  = b & 7;
    const int cp = (b >> 3) & 3;
    const int m  = b >> 5;            // 0..47
    const int p  = x * 48 + m;        // 0..383 unique
    const unsigned short *X, *W;
    unsigned short* C;
    int r0;
    if (p < 256)      { X = Fb;  W = Wbf;          C = Qb; r0 = p * 64; }
    else if (p < 320) { X = Tb;  W = Wbf + 262144; C = Kb; r0 = (p - 256) * 64; }
    else              { X = Ub0; W = Wbf + 524288; C = Vb; r0 = (p - 320) * 64; }
    const int c0 = cp * 128;

    const int tid = threadIdx.x;
    const int l  = tid & 63;
    const int wid = tid >> 6;
    const int wr = wid >> 1, wc = wid & 1;
    const int g = l >> 4;
    const int c = l & 15;

    f32x4 acc[2][4] = {};

    for (int k0 = 0; k0 < DM; k0 += 64) {
        #pragma unroll
        for (int i = 0; i < 2; ++i) {
            int idx = tid + i * 256;
            int row = idx >> 3, jj = idx & 7;
            int j = jj ^ (row & 7);
            gload16(X + (size_t)(r0 + row) * DM + k0 + j * 8, As + idx * 16);
        }
        #pragma unroll
        for (int i = 0; i < 4; ++i) {
            int idx = tid + i * 256;
            int row = idx >> 3, jj = idx & 7;
            int j = jj ^ (row & 7);
            gload16(W + (size_t)(c0 + row) * DM + k0 + j * 8, Bs + idx * 16);
        }
        __syncthreads();

        #pragma unroll
        for (int ks = 0; ks < 2; ++ks) {
            short8 af[2], bfr[4];
            #pragma unroll
            for (int mm = 0; mm < 2; ++mm) {
                int rq = wr * 32 + mm * 16 + c;
                af[mm] = *reinterpret_cast<short8*>(
                    As + ((rq * 128 + ks * 64 + g * 16) ^ ((rq & 7) << 4)));
            }
            #pragma unroll
            for (int n = 0; n < 4; ++n) {
                int rn = wc * 64 + n * 16 + c;
                bfr[n] = *reinterpret_cast<short8*>(
                    Bs + ((rn * 128 + ks * 64 + g * 16) ^ ((rn & 7) << 4)));
            }
            #pragma unroll
            for (int mm = 0; mm < 2; ++mm)
                #pragma unroll
                for (int n = 0; n < 4; ++n)
                    acc[mm][n] = __builtin_amdgcn_mfma_f32_16x16x32_bf16(
                        af[mm], bfr[n], acc[mm][n], 0, 0, 0);
        }
        __syncthreads();
    }

    #pragma unroll
    for (int mm = 0; mm < 2; ++mm)
        #pragma unroll
        for (int n = 0; n < 4; ++n)
            #pragma unroll
            for (int r = 0; r < 4; ++r)
                C[(size_t)(r0 + wr * 32 + mm * 16 + g * 4 + r) * DM +
                  c0 + wc * 64 + n * 16 + c] =
                    (unsigned short)cvtpk(acc[mm][n][r], acc[mm][n][r]);
}

// ---------------------------------------------------------------------------
// Out-projection, 64x128 tiles (4 blocks/CU), XCD-grouped.
// ---------------------------------------------------------------------------
__global__ __launch_bounds__(256) void gemm_bb(const unsigned short* __restrict__ X,
                                               const unsigned short* __restrict__ W,
                                               float* __restrict__ C) {
    __shared__ __align__(16) unsigned char smem[24576];
    unsigned char* As = smem;
    unsigned char* Bs = smem + 8192;

    const int b  = blockIdx.x;
    const int x  = b & 7;
    const int cp = (b >> 3) & 3;
    const int m  = b >> 5;            // 0..31
    const int p  = x * 32 + m;        // 0..255 unique
    const int r0 = p * 64;
    const int c0 = cp * 128;

    const int tid = threadIdx.x;
    const int l  = tid & 63;
    const int wid = tid >> 6;
    const int wr = wid >> 1, wc = wid & 1;
    const int g = l >> 4;
    const int c = l & 15;

    f32x4 acc[2][4] = {};

    for (int k0 = 0; k0 < DM; k0 += 64) {
        #pragma unroll
        for (int i = 0; i < 2; ++i) {
            int idx = tid + i * 256;
            int row = idx >> 3, jj = idx & 7;
            int j = jj ^ (row & 7);
            gload16(X + (size_t)(r0 + row) * DM + k0 + j * 8, As + idx * 16);
        }
        #pragma unroll
        for (int i = 0; i < 4; ++i) {
            int idx = tid + i * 256;
            int row = idx >> 3, jj = idx & 7;
            int j = jj ^ (row & 7);
            gload16(W + (size_t)(c0 + row) * DM + k0 + j * 8, Bs + idx * 16);
        }
        __syncthreads();

        #pragma unroll
        for (int ks = 0; ks < 2; ++ks) {
            short8 af[2], bfr[4];
            #pragma unroll
            for (int mm = 0; mm < 2; ++mm) {
                int rq = wr * 32 + mm * 16 + c;
                af[mm] = *reinterpret_cast<short8*>(
                    As + ((rq * 128 + ks * 64 + g * 16) ^ ((rq & 7) << 4)));
            }
            #pragma unroll
            for (int n = 0; n < 4; ++n) {
                int rn = wc * 64 + n * 16 + c;
                bfr[n] = *reinterpret_cast<short8*>(
                    Bs + ((rn * 128 + ks * 64 + g * 16) ^ ((rn & 7) << 4)));
            }
            #pragma unroll
            for (int mm = 0; mm < 2; ++mm)
                #pragma unroll
                for (int n = 0; n < 4; ++n)
                    acc[mm][n] = __builtin_amdgcn_mfma_f32_16x16x32_bf16(
                        af[mm], bfr[n], acc[mm][n], 0, 0, 0);
        }
        __syncthreads();
    }

    #pragma unroll
    for (int mm = 0; mm < 2; ++mm)
        #pragma unroll
        for (int n = 0; n < 4; ++n)
            #pragma unroll
            for (int r = 0; r < 4; ++r)
                C[(size_t)(r0 + wr * 32 + mm * 16 + g * 4 + r) * DM +
                  c0 + wc * 64 + n * 16 + c] = acc[mm][n][r];
}

// ---------------------------------------------------------------------------
// Merged normalize/pack launch, bf16 inputs: 5632 blocks.
// ---------------------------------------------------------------------------
__global__ __launch_bounds__(256) void normpack(const unsigned short* __restrict__ Qb,
                                                const unsigned short* __restrict__ Kb,
                                                const unsigned short* __restrict__ Vb,
                                                const float* __restrict__ qg,
                                                const float* __restrict__ kg,
                                                unsigned short* __restrict__ Qbf,
                                                unsigned short* __restrict__ Kbf,
                                                unsigned short* __restrict__ Vt) {
    __shared__ unsigned short vtile[64][68];
    const int bid = blockIdx.x;
    const int tid = threadIdx.x;

    if (bid < 5120) {
        const unsigned short* X; const float* gamma; unsigned short* Y;
        int rowbase; float sc;
        if (bid < 4096) { X = Qb; gamma = qg; Y = Qbf; rowbase = bid * 4; sc = 0.125f * LOG2E; }
        else            { X = Kb; gamma = kg; Y = Kbf; rowbase = (bid - 4096) * 4; sc = 1.0f; }

        const int wave = tid / 64;
        const int lane = tid % 64;
        const int row  = rowbase + wave;

        short8 xv = *reinterpret_cast<const short8*>(&X[(size_t)row * DM + lane * 8]);
        float x[8];
        #pragma unroll
        for (int i = 0; i < 8; ++i) x[i] = b2f((unsigned short)xv[i]);

        float s = 0.f;
        #pragma unroll
        for (int i = 0; i < 8; ++i) s += x[i];
        #pragma unroll
        for (int m = 1; m < 64; m <<= 1) s += __shfl_xor(s, m, 64);
        const float mu = s * (1.0f / 512.0f);

        float vs = 0.f;
        #pragma unroll
        for (int i = 0; i < 8; ++i) { float d = x[i] - mu; vs += d * d; }
        #pragma unroll
        for (int m = 1; m < 64; m <<= 1) vs += __shfl_xor(vs, m, 64);
        const float rs = rsqrtf(vs * (1.0f / 512.0f) + 1e-6f) * sc;

        float4 g0 = *reinterpret_cast<const float4*>(&gamma[lane * 8]);
        float4 g1 = *reinterpret_cast<const float4*>(&gamma[lane * 8 + 4]);
        float gv[8] = {g0.x, g0.y, g0.z, g0.w, g1.x, g1.y, g1.z, g1.w};

        float y[8];
        #pragma unroll
        for (int i = 0; i < 8; ++i) y[i] = (x[i] - mu) * rs * gv[i];
        uint4 o = make_uint4(cvtpk(y[0], y[1]), cvtpk(y[2], y[3]),
                             cvtpk(y[4], y[5]), cvtpk(y[6], y[7]));
        *reinterpret_cast<uint4*>(&Y[(size_t)row * DM + lane * 8]) = o;
    } else {
        const int b2 = bid - 5120;
        const int dt = b2 & 7, kt = (b2 >> 3) & 3, t = b2 >> 5;

        #pragma unroll
        for (int i = 0; i < 4; ++i) {
            int idx = tid + i * 256;
            int r = idx >> 4, c4 = idx & 15;
            uint2 v = *reinterpret_cast<const uint2*>(
                &Vb[(size_t)(t * M_ + kt * 64 + r) * DM + dt * 64 + c4 * 4]);
            *reinterpret_cast<uint2*>(&vtile[r][c4 * 4]) = v;
        }
        __syncthreads();
        #pragma unroll
        for (int i = 0; i < 4; ++i) {
            int idx = tid + i * 256;
            int r = idx >> 4, c4 = idx & 15;
            unsigned a0 = vtile[c4 * 4 + 0][r], a1 = vtile[c4 * 4 + 1][r];
            unsigned a2 = vtile[c4 * 4 + 2][r], a3 = vtile[c4 * 4 + 3][r];
            uint2 o = make_uint2(a0 | (a1 << 16), a2 | (a3 << 16));
            *reinterpret_cast<uint2*>(
                &Vt[((size_t)t * DM + dt * 64 + r) * M_ + kt * 64 + c4 * 4]) = o;
        }
    }
}

// ---------------------------------------------------------------------------
// MFMA attention: round-22 proven config (8 waves/block, 4 blocks/CU,
// no-max softmax with true bias, early-V, bare v_exp_f32).
// ---------------------------------------------------------------------------
__global__ __launch_bounds__(512, 4) void attn_mfma(const unsigned short* __restrict__ Qbf,
                                                    const unsigned short* __restrict__ Kbf,
                                                    const unsigned short* __restrict__ VtG,
                                                    const float* __restrict__ tracks,
                                                    const float* __restrict__ fpos,
                                                    unsigned short* __restrict__ Ubf) {
    const int b   = blockIdx.x;            // 0..1023
    const int xcd = b & 7;
    const int bi  = b >> 3;                // 0..127
    const int qt  = bi & 7;                // 128-q tile 0..7
    const int pp  = xcd + (bi >> 3) * 8;   // 0..127 = t*8 + h
    const int t   = pp >> 3;
    const int h   = pp & 7;
    const int q0  = qt * 128;
    const int tid = threadIdx.x;

    __shared__ __align__(16) unsigned char smem[32768 + 3072 + 1024];
    unsigned char* KV = smem;                        // K [256k][64d] / V [64dv][256k]
    float* tx4 = (float*)(smem + 32768);
    float* ty4 = (float*)(smem + 32768 + 1024);
    float* tz2 = (float*)(smem + 32768 + 2048);
    float* fps = (float*)(smem + 32768 + 3072);      // 128 q x {x,y}

    const int l  = tid & 63;
    const int wq = tid >> 6;    // 0..7
    const int g  = l >> 4;
    const int c  = l & 15;

    // ---- Q B-fragments (issued early; drained by first barrier) ----
    const unsigned short* qrow =
        Qbf + (size_t)(t * HW_ + q0 + wq * 16 + c) * DM + h * HEAD_;
    short8 bQ0 = *reinterpret_cast<const short8*>(qrow + g * 8);
    short8 bQ1 = *reinterpret_cast<const short8*>(qrow + 32 + g * 8);

    // ---- stage K via global_load_lds (512 threads -> 4 iters) ----
    #pragma unroll
    for (int it = 0; it < 4; ++it) {
        int idx = tid + it * 512;               // 0..2047
        int row = idx >> 3, jj = idx & 7;
        int j = jj ^ (row & 7);
        gload16(Kbf + (size_t)(t * M_ + row) * DM + h * HEAD_ + j * 8, KV + idx * 16);
    }
    if (tid < 256) {
        float2 tk = *reinterpret_cast<const float2*>(&tracks[t * 512 + tid * 2]);
        tx4[tid] = tk.x * (4.0f * LOG2E);
        ty4[tid] = tk.y * (4.0f * LOG2E);
        tz2[tid] = -2.0f * LOG2E * (tk.x * tk.x + tk.y * tk.y);
        fps[tid] = fpos[q0 * 2 + tid];          // 256 floats = 128 q positions
    }
    __syncthreads();

    // ---- scores^T: acc[n][r] = S[key=n*16+g*4+r][q=q0+wq*16+c] ----
    f32x4 acc[16];
    __builtin_amdgcn_s_setprio(1);
    #pragma unroll
    for (int n = 0; n < 16; ++n) {
        int rk = n * 16 + c;
        short8 a0 = *reinterpret_cast<short8*>(KV + ((rk * 128 + g * 16) ^ ((rk & 7) << 4)));
        short8 a1 = *reinterpret_cast<short8*>(KV + ((rk * 128 + 64 + g * 16) ^ ((rk & 7) << 4)));
        f32x4 z = {0.f, 0.f, 0.f, 0.f};
        z = __builtin_amdgcn_mfma_f32_16x16x32_bf16(a0, bQ0, z, 0, 0, 0);
        z = __builtin_amdgcn_mfma_f32_16x16x32_bf16(a1, bQ1, z, 0, 0, 0);
        acc[n] = z;
    }
    __builtin_amdgcn_s_setprio(0);

    __syncthreads();   // all waves done reading K -> safe to overwrite with V

    // ---- issue V staging NOW; latency hides under bias+exp2+pack+sum ----
    #pragma unroll
    for (int it = 0; it < 4; ++it) {
        int idx = tid + it * 512;               // 0..2047
        int row = idx >> 5, kcc = idx & 31;
        int kc = kcc ^ (row & 7);
        gload16(VtG + ((size_t)t * DM + h * HEAD_ + row) * M_ + kc * 8, KV + idx * 16);
    }

    // ---- bias + exp2 + pack + per-n partial sums (no max; per-n ILP) ----
    const float fx = fps[(wq * 16 + c) * 2];
    const float fy = fps[(wq * 16 + c) * 2 + 1];
    const float fz = -2.0f * LOG2E * (fx * fx + fy * fy);   // true-bias term
    unsigned pk[16][2];
    float vr[16];
    #pragma unroll
    for (int n = 0; n < 16; ++n) {
        float4 x4 = *reinterpret_cast<float4*>(&tx4[n * 16 + g * 4]);
        float4 y4 = *reinterpret_cast<float4*>(&ty4[n * 16 + g * 4]);
        float4 z4 = *reinterpret_cast<float4*>(&tz2[n * 16 + g * 4]);
        float e0 = fexp2((acc[n][0] + fz) + fmaf(fx, x4.x, fmaf(fy, y4.x, z4.x)));
        float e1 = fexp2((acc[n][1] + fz) + fmaf(fx, x4.y, fmaf(fy, y4.y, z4.y)));
        float e2 = fexp2((acc[n][2] + fz) + fmaf(fx, x4.z, fmaf(fy, y4.z, z4.z)));
        float e3 = fexp2((acc[n][3] + fz) + fmaf(fx, x4.w, fmaf(fy, y4.w, z4.w)));
        pk[n][0] = cvtpk(e0, e1);
        pk[n][1] = cvtpk(e2, e3);
        vr[n] = (e0 + e1) + (e2 + e3);
    }

    // ---- sum tree + cross-g reduce; inv applied at output ----
    #pragma unroll
    for (int s = 8; s >= 1; s >>= 1)
        #pragma unroll
        for (int n = 0; n < 8; ++n)
            if (n < s) vr[n] += vr[n + s];
    float sum = vr[0];
    sum += __shfl_xor(sum, 16, 64);
    sum += __shfl_xor(sum, 32, 64);
    const float inv = 1.0f / sum;    // row q = q0 + wq*16 + c

    // output rows are q = q0 + wq*16 + g*4 + r -> fetch inv from lane c'=g*4+r
    float invr[4];
    #pragma unroll
    for (int r = 0; r < 4; ++r)
        invr[r] = __shfl(inv, (l & 48) | ((l >> 2) & 12) | r, 64);

    __syncthreads();   // V staged (barrier drains vmcnt)

    // ---- PV ----
    f32x4 o[4] = {{0.f,0.f,0.f,0.f},{0.f,0.f,0.f,0.f},{0.f,0.f,0.f,0.f},{0.f,0.f,0.f,0.f}};
    __builtin_amdgcn_s_setprio(1);
    #pragma unroll
    for (int ks = 0; ks < 8; ++ks) {
        unsigned wb[4];
        #pragma unroll
        for (int wt = 0; wt < 4; ++wt) {
            int src = ((l & 16) << 1) + (wt >> 1) * 16 + c;
            unsigned ve = (unsigned)__shfl((int)pk[2 * ks][wt & 1], src, 64);
            unsigned vo = (unsigned)__shfl((int)pk[2 * ks + 1][wt & 1], src, 64);
            wb[wt] = (g < 2) ? ve : vo;
        }
        uint4 uu = make_uint4(wb[0], wb[1], wb[2], wb[3]);
        short8 aP = *reinterpret_cast<short8*>(&uu);
        #pragma unroll
        for (int nv = 0; nv < 4; ++nv) {
            int rv = nv * 16 + c;
            short8 bV = *reinterpret_cast<short8*>(
                KV + ((rv * 512 + ks * 64 + g * 16) ^ ((rv & 7) << 4)));
            o[nv] = __builtin_amdgcn_mfma_f32_16x16x32_bf16(aP, bV, o[nv], 0, 0, 0);
        }
    }
    __builtin_amdgcn_s_setprio(0);

    #pragma unroll
    for (int nv = 0; nv < 4; ++nv)
        #pragma unroll
        for (int r = 0; r < 4; ++r) {
            float xo = o[nv][r] * invr[r];
            Ubf[(size_t)(t * HW_ + q0 + wq * 16 + g * 4 + r) * DM +
                h * HEAD_ + nv * 16 + c] = (unsigned short)cvtpk(xo, xo);
        }
}

// ---------------------------------------------------------------------------
extern "C" void kernel_launch(void* const* d_in, const int* in_sizes, int n_in,
                              void* d_out, int out_size, void* d_ws, size_t ws_size,
                              hipStream_t stream) {
    const float* utt    = (const float*)d_in[0];
    const float* tracks = (const float*)d_in[1];
    const float* fpos   = (const float*)d_in[2];
    const float* fpe    = (const float*)d_in[3];
    const float* tpe    = (const float*)d_in[4];
    const float* Wq     = (const float*)d_in[5];
    const float* Wk     = (const float*)d_in[6];
    const float* Wv     = (const float*)d_in[7];
    const float* Wo     = (const float*)d_in[8];
    const float* qgamma = (const float*)d_in[9];
    const float* kgamma = (const float*)d_in[10];
    float* out = (float*)d_out;

    char* ws = (char*)d_ws;
    unsigned short* Fb  = (unsigned short*)(ws);              // [0, 16.8M) bf16 fpe
    unsigned short* Tb  = (unsigned short*)(ws + 16777216);   // [16.8, 21.0) bf16 tpe
    unsigned short* Ub0 = (unsigned short*)(ws + 20971520);   // [21.0, 25.2) bf16 utt
    unsigned short* Qb  = (unsigned short*)(ws + 25165824);   // [25.2, 42.0) proj Q
    unsigned short* Kb  = (unsigned short*)(ws + 41943040);   // [42.0, 46.1) proj K
    unsigned short* Vb  = (unsigned short*)(ws + 46137344);   // [46.1, 50.3) proj V
    unsigned short* Qbf = (unsigned short*)(ws + 50331648);   // [50.3, 67.1) LN-Q
    unsigned short* Kbf = (unsigned short*)(ws + 67108864);   // [67.1, 71.3) LN-K
    unsigned short* Vt  = (unsigned short*)(ws + 71303168);   // [71.3, 75.5) V^T
    unsigned short* Wbf = (unsigned short*)(ws + 75497472);   // [75.5, 77.6) weights
    unsigned short* Ubf = (unsigned short*)(ws);              // overlays Fb (dead after proj3)

    // 1) all f32 -> bf16 conversions (memory-bound single pass)
    cvtall<<<6656, 256, 0, stream>>>(fpe, tpe, utt, Wq, Wk, Wv, Wo, Fb, Tb, Ub0, Wbf);

    // 2) Q/K/V projections -> bf16 (64x128 tiles, 6 blocks/CU)
    proj3<<<1536, 256, 0, stream>>>(Fb, Tb, Ub0, Wbf, Qb, Kb, Vb);

    // 3) LN-Q, LN-K, V-transpose (bf16 in, bf16 out)
    normpack<<<5632, 256, 0, stream>>>(Qb, Kb, Vb, qgamma, kgamma, Qbf, Kbf, Vt);

    // 4) fused MFMA attention, 8 waves/block, 4 blocks/CU (overlays dead Fb)
    attn_mfma<<<1024, 512, 0, stream>>>(Qbf, Kbf, Vt, tracks, fpos, Ubf);

    // 5) out projection (64x128 tiles, 4 blocks/CU)
    gemm_bb<<<1024, 256, 0, stream>>>(Ubf, Wbf + 786432, out);
}

// Round 25
// 88.230 us; speedup vs baseline: 1.0438x; 1.0104x over previous
//
#include <hip/hip_runtime.h>

#define T_    16
#define M_    256
#define HW_   1024
#define DM    512
#define H_    8
#define HEAD_ 64
#define LOG2E 1.4426950408889634f

typedef __attribute__((ext_vector_type(8))) short short8;
typedef __attribute__((ext_vector_type(4))) float f32x4;

__device__ __forceinline__ unsigned cvtpk(float lo, float hi) {
    unsigned r;
    asm("v_cvt_pk_bf16_f32 %0, %1, %2" : "=v"(r) : "v"(lo), "v"(hi));
    return r;
}

// bare v_exp_f32 (2^x); s_nop 1 covers the TRANS->VALU read hazard.
__device__ __forceinline__ float fexp2(float x) {
    float r;
    asm("v_exp_f32 %0, %1\n\ts_nop 1" : "=v"(r) : "v"(x));
    return r;
}

__device__ __forceinline__ float b2f(unsigned short u) {
    return __uint_as_float(((unsigned)u) << 16);
}

__device__ __forceinline__ void gload16(const void* g, void* l) {
    __builtin_amdgcn_global_load_lds(
        (const __attribute__((address_space(1))) void*)g,
        (__attribute__((address_space(3))) void*)l, 16, 0, 0);
}

// ---------------------------------------------------------------------------
// Convert all f32 operands to bf16 in one memory-bound pass.
// ---------------------------------------------------------------------------
__global__ __launch_bounds__(256) void cvtall(const float* __restrict__ fpe,
                                              const float* __restrict__ tpe,
                                              const float* __restrict__ utt,
                                              const float* __restrict__ Wq,
                                              const float* __restrict__ Wk,
                                              const float* __restrict__ Wv,
                                              const float* __restrict__ Wo,
                                              unsigned short* __restrict__ Fb,
                                              unsigned short* __restrict__ Tb,
                                              unsigned short* __restrict__ Ub0,
                                              unsigned short* __restrict__ Wbf) {
    size_t e = (size_t)(blockIdx.x * 256 + threadIdx.x) * 8;
    const float* s;
    unsigned short* d;
    if (e < 8388608)        { s = fpe + e;              d = Fb  + e; }
    else if (e < 10485760)  { s = tpe + (e - 8388608);  d = Tb  + (e - 8388608); }
    else if (e < 12582912)  { s = utt + (e - 10485760); d = Ub0 + (e - 10485760); }
    else if (e < 12845056)  { s = Wq  + (e - 12582912); d = Wbf + (e - 12582912 + 0); }
    else if (e < 13107200)  { s = Wk  + (e - 12845056); d = Wbf + (e - 12845056 + 262144); }
    else if (e < 13369344)  { s = Wv  + (e - 13107200); d = Wbf + (e - 13107200 + 524288); }
    else                    { s = Wo  + (e - 13369344); d = Wbf + (e - 13369344 + 786432); }
    float4 a = *reinterpret_cast<const float4*>(s);
    float4 b = *reinterpret_cast<const float4*>(s + 4);
    uint4 v = make_uint4(cvtpk(a.x, a.y), cvtpk(a.z, a.w),
                         cvtpk(b.x, b.y), cvtpk(b.z, b.w));
    *reinterpret_cast<uint4*>(d) = v;
}

// ---------------------------------------------------------------------------
// Merged Q/K/V projections, 64x128 tiles (6 blocks/CU), XCD-grouped.
// ---------------------------------------------------------------------------
__global__ __launch_bounds__(256) void proj3(const unsigned short* __restrict__ Fb,
                                             const unsigned short* __restrict__ Tb,
                                             const unsigned short* __restrict__ Ub0,
                                             const unsigned short* __restrict__ Wbf,
                                             unsigned short* __restrict__ Qb,
                                             unsigned short* __restrict__ Kb,
                                             unsigned short* __restrict__ Vb) {
    __shared__ __align__(16) unsigned char smem[24576];
    unsigned char* As = smem;            // [64 r][64 k] bf16 swz
    unsigned char* Bs = smem + 8192;     // [128 c][64 k] bf16 swz

    const int b  = blockIdx.x;
    const int x  = b & 7;
    const int cp = (b >> 3) & 3;
    const int m  = b >> 5;            // 0..47
    const int p  = x * 48 + m;        // 0..383 unique
    const unsigned short *X, *W;
    unsigned short* C;
    int r0;
    if (p < 256)      { X = Fb;  W = Wbf;          C = Qb; r0 = p * 64; }
    else if (p < 320) { X = Tb;  W = Wbf + 262144; C = Kb; r0 = (p - 256) * 64; }
    else              { X = Ub0; W = Wbf + 524288; C = Vb; r0 = (p - 320) * 64; }
    const int c0 = cp * 128;

    const int tid = threadIdx.x;
    const int l  = tid & 63;
    const int wid = tid >> 6;
    const int wr = wid >> 1, wc = wid & 1;
    const int g = l >> 4;
    const int c = l & 15;

    f32x4 acc[2][4] = {};

    for (int k0 = 0; k0 < DM; k0 += 64) {
        #pragma unroll
        for (int i = 0; i < 2; ++i) {
            int idx = tid + i * 256;
            int row = idx >> 3, jj = idx & 7;
            int j = jj ^ (row & 7);
            gload16(X + (size_t)(r0 + row) * DM + k0 + j * 8, As + idx * 16);
        }
        #pragma unroll
        for (int i = 0; i < 4; ++i) {
            int idx = tid + i * 256;
            int row = idx >> 3, jj = idx & 7;
            int j = jj ^ (row & 7);
            gload16(W + (size_t)(c0 + row) * DM + k0 + j * 8, Bs + idx * 16);
        }
        __syncthreads();

        #pragma unroll
        for (int ks = 0; ks < 2; ++ks) {
            short8 af[2], bfr[4];
            #pragma unroll
            for (int mm = 0; mm < 2; ++mm) {
                int rq = wr * 32 + mm * 16 + c;
                af[mm] = *reinterpret_cast<short8*>(
                    As + ((rq * 128 + ks * 64 + g * 16) ^ ((rq & 7) << 4)));
            }
            #pragma unroll
            for (int n = 0; n < 4; ++n) {
                int rn = wc * 64 + n * 16 + c;
                bfr[n] = *reinterpret_cast<short8*>(
                    Bs + ((rn * 128 + ks * 64 + g * 16) ^ ((rn & 7) << 4)));
            }
            #pragma unroll
            for (int mm = 0; mm < 2; ++mm)
                #pragma unroll
                for (int n = 0; n < 4; ++n)
                    acc[mm][n] = __builtin_amdgcn_mfma_f32_16x16x32_bf16(
                        af[mm], bfr[n], acc[mm][n], 0, 0, 0);
        }
        __syncthreads();
    }

    #pragma unroll
    for (int mm = 0; mm < 2; ++mm)
        #pragma unroll
        for (int n = 0; n < 4; ++n)
            #pragma unroll
            for (int r = 0; r < 4; ++r)
                C[(size_t)(r0 + wr * 32 + mm * 16 + g * 4 + r) * DM +
                  c0 + wc * 64 + n * 16 + c] =
                    (unsigned short)cvtpk(acc[mm][n][r], acc[mm][n][r]);
}

// ---------------------------------------------------------------------------
// Out-projection, 64x128 tiles (4 blocks/CU), XCD-grouped.
// ---------------------------------------------------------------------------
__global__ __launch_bounds__(256) void gemm_bb(const unsigned short* __restrict__ X,
                                               const unsigned short* __restrict__ W,
                                               float* __restrict__ C) {
    __shared__ __align__(16) unsigned char smem[24576];
    unsigned char* As = smem;
    unsigned char* Bs = smem + 8192;

    const int b  = blockIdx.x;
    const int x  = b & 7;
    const int cp = (b >> 3) & 3;
    const int m  = b >> 5;            // 0..31
    const int p  = x * 32 + m;        // 0..255 unique
    const int r0 = p * 64;
    const int c0 = cp * 128;

    const int tid = threadIdx.x;
    const int l  = tid & 63;
    const int wid = tid >> 6;
    const int wr = wid >> 1, wc = wid & 1;
    const int g = l >> 4;
    const int c = l & 15;

    f32x4 acc[2][4] = {};

    for (int k0 = 0; k0 < DM; k0 += 64) {
        #pragma unroll
        for (int i = 0; i < 2; ++i) {
            int idx = tid + i * 256;
            int row = idx >> 3, jj = idx & 7;
            int j = jj ^ (row & 7);
            gload16(X + (size_t)(r0 + row) * DM + k0 + j * 8, As + idx * 16);
        }
        #pragma unroll
        for (int i = 0; i < 4; ++i) {
            int idx = tid + i * 256;
            int row = idx >> 3, jj = idx & 7;
            int j = jj ^ (row & 7);
            gload16(W + (size_t)(c0 + row) * DM + k0 + j * 8, Bs + idx * 16);
        }
        __syncthreads();

        #pragma unroll
        for (int ks = 0; ks < 2; ++ks) {
            short8 af[2], bfr[4];
            #pragma unroll
            for (int mm = 0; mm < 2; ++mm) {
                int rq = wr * 32 + mm * 16 + c;
                af[mm] = *reinterpret_cast<short8*>(
                    As + ((rq * 128 + ks * 64 + g * 16) ^ ((rq & 7) << 4)));
            }
            #pragma unroll
            for (int n = 0; n < 4; ++n) {
                int rn = wc * 64 + n * 16 + c;
                bfr[n] = *reinterpret_cast<short8*>(
                    Bs + ((rn * 128 + ks * 64 + g * 16) ^ ((rn & 7) << 4)));
            }
            #pragma unroll
            for (int mm = 0; mm < 2; ++mm)
                #pragma unroll
                for (int n = 0; n < 4; ++n)
                    acc[mm][n] = __builtin_amdgcn_mfma_f32_16x16x32_bf16(
                        af[mm], bfr[n], acc[mm][n], 0, 0, 0);
        }
        __syncthreads();
    }

    #pragma unroll
    for (int mm = 0; mm < 2; ++mm)
        #pragma unroll
        for (int n = 0; n < 4; ++n)
            #pragma unroll
            for (int r = 0; r < 4; ++r)
                C[(size_t)(r0 + wr * 32 + mm * 16 + g * 4 + r) * DM +
                  c0 + wc * 64 + n * 16 + c] = acc[mm][n][r];
}

// ---------------------------------------------------------------------------
// Merged normalize/pack launch, bf16 inputs: 5632 blocks.
// ---------------------------------------------------------------------------
__global__ __launch_bounds__(256) void normpack(const unsigned short* __restrict__ Qb,
                                                const unsigned short* __restrict__ Kb,
                                                const unsigned short* __restrict__ Vb,
                                                const float* __restrict__ qg,
                                                const float* __restrict__ kg,
                                                unsigned short* __restrict__ Qbf,
                                                unsigned short* __restrict__ Kbf,
                                                unsigned short* __restrict__ Vt) {
    __shared__ unsigned short vtile[64][68];
    const int bid = blockIdx.x;
    const int tid = threadIdx.x;

    if (bid < 5120) {
        const unsigned short* X; const float* gamma; unsigned short* Y;
        int rowbase; float sc;
        if (bid < 4096) { X = Qb; gamma = qg; Y = Qbf; rowbase = bid * 4; sc = 0.125f * LOG2E; }
        else            { X = Kb; gamma = kg; Y = Kbf; rowbase = (bid - 4096) * 4; sc = 1.0f; }

        const int wave = tid / 64;
        const int lane = tid % 64;
        const int row  = rowbase + wave;

        short8 xv = *reinterpret_cast<const short8*>(&X[(size_t)row * DM + lane * 8]);
        float x[8];
        #pragma unroll
        for (int i = 0; i < 8; ++i) x[i] = b2f((unsigned short)xv[i]);

        float s = 0.f;
        #pragma unroll
        for (int i = 0; i < 8; ++i) s += x[i];
        #pragma unroll
        for (int m = 1; m < 64; m <<= 1) s += __shfl_xor(s, m, 64);
        const float mu = s * (1.0f / 512.0f);

        float vs = 0.f;
        #pragma unroll
        for (int i = 0; i < 8; ++i) { float d = x[i] - mu; vs += d * d; }
        #pragma unroll
        for (int m = 1; m < 64; m <<= 1) vs += __shfl_xor(vs, m, 64);
        const float rs = rsqrtf(vs * (1.0f / 512.0f) + 1e-6f) * sc;

        float4 g0 = *reinterpret_cast<const float4*>(&gamma[lane * 8]);
        float4 g1 = *reinterpret_cast<const float4*>(&gamma[lane * 8 + 4]);
        float gv[8] = {g0.x, g0.y, g0.z, g0.w, g1.x, g1.y, g1.z, g1.w};

        float y[8];
        #pragma unroll
        for (int i = 0; i < 8; ++i) y[i] = (x[i] - mu) * rs * gv[i];
        uint4 o = make_uint4(cvtpk(y[0], y[1]), cvtpk(y[2], y[3]),
                             cvtpk(y[4], y[5]), cvtpk(y[6], y[7]));
        *reinterpret_cast<uint4*>(&Y[(size_t)row * DM + lane * 8]) = o;
    } else {
        const int b2 = bid - 5120;
        const int dt = b2 & 7, kt = (b2 >> 3) & 3, t = b2 >> 5;

        #pragma unroll
        for (int i = 0; i < 4; ++i) {
            int idx = tid + i * 256;
            int r = idx >> 4, c4 = idx & 15;
            uint2 v = *reinterpret_cast<const uint2*>(
                &Vb[(size_t)(t * M_ + kt * 64 + r) * DM + dt * 64 + c4 * 4]);
            *reinterpret_cast<uint2*>(&vtile[r][c4 * 4]) = v;
        }
        __syncthreads();
        #pragma unroll
        for (int i = 0; i < 4; ++i) {
            int idx = tid + i * 256;
            int r = idx >> 4, c4 = idx & 15;
            unsigned a0 = vtile[c4 * 4 + 0][r], a1 = vtile[c4 * 4 + 1][r];
            unsigned a2 = vtile[c4 * 4 + 2][r], a3 = vtile[c4 * 4 + 3][r];
            uint2 o = make_uint2(a0 | (a1 << 16), a2 | (a3 << 16));
            *reinterpret_cast<uint2*>(
                &Vt[((size_t)t * DM + dt * 64 + r) * M_ + kt * 64 + c4 * 4]) = o;
        }
    }
}

// ---------------------------------------------------------------------------
// MFMA attention: round-24 config MINUS s_setprio (m190: setprio is
// null-to-negative on barrier-synced lockstep structures; this kernel is
// an 8-wave 3-barrier lockstep, i.e. the GEMM-like regime).
// ---------------------------------------------------------------------------
__global__ __launch_bounds__(512, 4) void attn_mfma(const unsigned short* __restrict__ Qbf,
                                                    const unsigned short* __restrict__ Kbf,
                                                    const unsigned short* __restrict__ VtG,
                                                    const float* __restrict__ tracks,
                                                    const float* __restrict__ fpos,
                                                    unsigned short* __restrict__ Ubf) {
    const int b   = blockIdx.x;            // 0..1023
    const int xcd = b & 7;
    const int bi  = b >> 3;                // 0..127
    const int qt  = bi & 7;                // 128-q tile 0..7
    const int pp  = xcd + (bi >> 3) * 8;   // 0..127 = t*8 + h
    const int t   = pp >> 3;
    const int h   = pp & 7;
    const int q0  = qt * 128;
    const int tid = threadIdx.x;

    __shared__ __align__(16) unsigned char smem[32768 + 3072 + 1024];
    unsigned char* KV = smem;                        // K [256k][64d] / V [64dv][256k]
    float* tx4 = (float*)(smem + 32768);
    float* ty4 = (float*)(smem + 32768 + 1024);
    float* tz2 = (float*)(smem + 32768 + 2048);
    float* fps = (float*)(smem + 32768 + 3072);      // 128 q x {x,y}

    const int l  = tid & 63;
    const int wq = tid >> 6;    // 0..7
    const int g  = l >> 4;
    const int c  = l & 15;

    // ---- Q B-fragments (issued early; drained by first barrier) ----
    const unsigned short* qrow =
        Qbf + (size_t)(t * HW_ + q0 + wq * 16 + c) * DM + h * HEAD_;
    short8 bQ0 = *reinterpret_cast<const short8*>(qrow + g * 8);
    short8 bQ1 = *reinterpret_cast<const short8*>(qrow + 32 + g * 8);

    // ---- stage K via global_load_lds (512 threads -> 4 iters) ----
    #pragma unroll
    for (int it = 0; it < 4; ++it) {
        int idx = tid + it * 512;               // 0..2047
        int row = idx >> 3, jj = idx & 7;
        int j = jj ^ (row & 7);
        gload16(Kbf + (size_t)(t * M_ + row) * DM + h * HEAD_ + j * 8, KV + idx * 16);
    }
    if (tid < 256) {
        float2 tk = *reinterpret_cast<const float2*>(&tracks[t * 512 + tid * 2]);
        tx4[tid] = tk.x * (4.0f * LOG2E);
        ty4[tid] = tk.y * (4.0f * LOG2E);
        tz2[tid] = -2.0f * LOG2E * (tk.x * tk.x + tk.y * tk.y);
        fps[tid] = fpos[q0 * 2 + tid];          // 256 floats = 128 q positions
    }
    __syncthreads();

    // ---- scores^T: acc[n][r] = S[key=n*16+g*4+r][q=q0+wq*16+c] ----
    f32x4 acc[16];
    #pragma unroll
    for (int n = 0; n < 16; ++n) {
        int rk = n * 16 + c;
        short8 a0 = *reinterpret_cast<short8*>(KV + ((rk * 128 + g * 16) ^ ((rk & 7) << 4)));
        short8 a1 = *reinterpret_cast<short8*>(KV + ((rk * 128 + 64 + g * 16) ^ ((rk & 7) << 4)));
        f32x4 z = {0.f, 0.f, 0.f, 0.f};
        z = __builtin_amdgcn_mfma_f32_16x16x32_bf16(a0, bQ0, z, 0, 0, 0);
        z = __builtin_amdgcn_mfma_f32_16x16x32_bf16(a1, bQ1, z, 0, 0, 0);
        acc[n] = z;
    }

    __syncthreads();   // all waves done reading K -> safe to overwrite with V

    // ---- issue V staging NOW; latency hides under bias+exp2+pack+sum ----
    #pragma unroll
    for (int it = 0; it < 4; ++it) {
        int idx = tid + it * 512;               // 0..2047
        int row = idx >> 5, kcc = idx & 31;
        int kc = kcc ^ (row & 7);
        gload16(VtG + ((size_t)t * DM + h * HEAD_ + row) * M_ + kc * 8, KV + idx * 16);
    }

    // ---- bias + exp2 + pack + per-n partial sums (no max; per-n ILP) ----
    const float fx = fps[(wq * 16 + c) * 2];
    const float fy = fps[(wq * 16 + c) * 2 + 1];
    const float fz = -2.0f * LOG2E * (fx * fx + fy * fy);   // true-bias term
    unsigned pk[16][2];
    float vr[16];
    #pragma unroll
    for (int n = 0; n < 16; ++n) {
        float4 x4 = *reinterpret_cast<float4*>(&tx4[n * 16 + g * 4]);
        float4 y4 = *reinterpret_cast<float4*>(&ty4[n * 16 + g * 4]);
        float4 z4 = *reinterpret_cast<float4*>(&tz2[n * 16 + g * 4]);
        float e0 = fexp2((acc[n][0] + fz) + fmaf(fx, x4.x, fmaf(fy, y4.x, z4.x)));
        float e1 = fexp2((acc[n][1] + fz) + fmaf(fx, x4.y, fmaf(fy, y4.y, z4.y)));
        float e2 = fexp2((acc[n][2] + fz) + fmaf(fx, x4.z, fmaf(fy, y4.z, z4.z)));
        float e3 = fexp2((acc[n][3] + fz) + fmaf(fx, x4.w, fmaf(fy, y4.w, z4.w)));
        pk[n][0] = cvtpk(e0, e1);
        pk[n][1] = cvtpk(e2, e3);
        vr[n] = (e0 + e1) + (e2 + e3);
    }

    // ---- sum tree + cross-g reduce; inv applied at output ----
    #pragma unroll
    for (int s = 8; s >= 1; s >>= 1)
        #pragma unroll
        for (int n = 0; n < 8; ++n)
            if (n < s) vr[n] += vr[n + s];
    float sum = vr[0];
    sum += __shfl_xor(sum, 16, 64);
    sum += __shfl_xor(sum, 32, 64);
    const float inv = 1.0f / sum;    // row q = q0 + wq*16 + c

    // output rows are q = q0 + wq*16 + g*4 + r -> fetch inv from lane c'=g*4+r
    float invr[4];
    #pragma unroll
    for (int r = 0; r < 4; ++r)
        invr[r] = __shfl(inv, (l & 48) | ((l >> 2) & 12) | r, 64);

    __syncthreads();   // V staged (barrier drains vmcnt)

    // ---- PV ----
    f32x4 o[4] = {{0.f,0.f,0.f,0.f},{0.f,0.f,0.f,0.f},{0.f,0.f,0.f,0.f},{0.f,0.f,0.f,0.f}};
    #pragma unroll
    for (int ks = 0; ks < 8; ++ks) {
        unsigned wb[4];
        #pragma unroll
        for (int wt = 0; wt < 4; ++wt) {
            int src = ((l & 16) << 1) + (wt >> 1) * 16 + c;
            unsigned ve = (unsigned)__shfl((int)pk[2 * ks][wt & 1], src, 64);
            unsigned vo = (unsigned)__shfl((int)pk[2 * ks + 1][wt & 1], src, 64);
            wb[wt] = (g < 2) ? ve : vo;
        }
        uint4 uu = make_uint4(wb[0], wb[1], wb[2], wb[3]);
        short8 aP = *reinterpret_cast<short8*>(&uu);
        #pragma unroll
        for (int nv = 0; nv < 4; ++nv) {
            int rv = nv * 16 + c;
            short8 bV = *reinterpret_cast<short8*>(
                KV + ((rv * 512 + ks * 64 + g * 16) ^ ((rv & 7) << 4)));
            o[nv] = __builtin_amdgcn_mfma_f32_16x16x32_bf16(aP, bV, o[nv], 0, 0, 0);
        }
    }

    #pragma unroll
    for (int nv = 0; nv < 4; ++nv)
        #pragma unroll
        for (int r = 0; r < 4; ++r) {
            float xo = o[nv][r] * invr[r];
            Ubf[(size_t)(t * HW_ + q0 + wq * 16 + g * 4 + r) * DM +
                h * HEAD_ + nv * 16 + c] = (unsigned short)cvtpk(xo, xo);
        }
}

// ---------------------------------------------------------------------------
extern "C" void kernel_launch(void* const* d_in, const int* in_sizes, int n_in,
                              void* d_out, int out_size, void* d_ws, size_t ws_size,
                              hipStream_t stream) {
    const float* utt    = (const float*)d_in[0];
    const float* tracks = (const float*)d_in[1];
    const float* fpos   = (const float*)d_in[2];
    const float* fpe    = (const float*)d_in[3];
    const float* tpe    = (const float*)d_in[4];
    const float* Wq     = (const float*)d_in[5];
    const float* Wk     = (const float*)d_in[6];
    const float* Wv     = (const float*)d_in[7];
    const float* Wo     = (const float*)d_in[8];
    const float* qgamma = (const float*)d_in[9];
    const float* kgamma = (const float*)d_in[10];
    float* out = (float*)d_out;

    char* ws = (char*)d_ws;
    unsigned short* Fb  = (unsigned short*)(ws);              // [0, 16.8M) bf16 fpe
    unsigned short* Tb  = (unsigned short*)(ws + 16777216);   // [16.8, 21.0) bf16 tpe
    unsigned short* Ub0 = (unsigned short*)(ws + 20971520);   // [21.0, 25.2) bf16 utt
    unsigned short* Qb  = (unsigned short*)(ws + 25165824);   // [25.2, 42.0) proj Q
    unsigned short* Kb  = (unsigned short*)(ws + 41943040);   // [42.0, 46.1) proj K
    unsigned short* Vb  = (unsigned short*)(ws + 46137344);   // [46.1, 50.3) proj V
    unsigned short* Qbf = (unsigned short*)(ws + 50331648);   // [50.3, 67.1) LN-Q
    unsigned short* Kbf = (unsigned short*)(ws + 67108864);   // [67.1, 71.3) LN-K
    unsigned short* Vt  = (unsigned short*)(ws + 71303168);   // [71.3, 75.5) V^T
    unsigned short* Wbf = (unsigned short*)(ws + 75497472);   // [75.5, 77.6) weights
    unsigned short* Ubf = (unsigned short*)(ws);              // overlays Fb (dead after proj3)

    // 1) all f32 -> bf16 conversions (memory-bound single pass)
    cvtall<<<6656, 256, 0, stream>>>(fpe, tpe, utt, Wq, Wk, Wv, Wo, Fb, Tb, Ub0, Wbf);

    // 2) Q/K/V projections -> bf16 (64x128 tiles, 6 blocks/CU)
    proj3<<<1536, 256, 0, stream>>>(Fb, Tb, Ub0, Wbf, Qb, Kb, Vb);

    // 3) LN-Q, LN-K, V-transpose (bf16 in, bf16 out)
    normpack<<<5632, 256, 0, stream>>>(Qb, Kb, Vb, qgamma, kgamma, Qbf, Kbf, Vt);

    // 4) fused MFMA attention, 8 waves/block, 4 blocks/CU (overlays dead Fb)
    attn_mfma<<<1024, 512, 0, stream>>>(Qbf, Kbf, Vt, tracks, fpos, Ubf);

    // 5) out projection (64x128 tiles, 4 blocks/CU)
    gemm_bb<<<1024, 256, 0, stream>>>(Ubf, Wbf + 786432, out);
}